// Round 12
// baseline (174.166 us; speedup 1.0000x reference)
//
#include <hip/hip_runtime.h>
#include <math.h>

typedef __attribute__((ext_vector_type(4))) float f32x4;
typedef __attribute__((ext_vector_type(2))) float f32x2;
typedef __attribute__((ext_vector_type(8))) __bf16 bf16x8;
typedef __attribute__((ext_vector_type(4))) __bf16 bf16x4;
typedef __attribute__((ext_vector_type(2))) __bf16 bf16x2;

// ---------------- path tables (order matches Python PATHS enumeration) ----------
__device__ __constant__ int GP_L[34]  = {0,0,0,0, 1,1,1,1,1,1,1,1,1, 2,2,2,2,2,2,2,2,2,2,2, 3,3,3,3,3,3,3,3,3,3};
__device__ __constant__ int GP_L1[34] = {0,1,2,3, 0,1,1,1,2,2,2,3,3, 0,1,1,1,2,2,2,2,3,3,3, 0,1,1,2,2,2,3,3,3,3};
__device__ __constant__ int GP_L2[34] = {0,1,2,3, 1,0,1,2,1,2,3,2,3, 2,1,2,3,0,1,2,3,1,2,3, 3,2,3,1,2,3,0,1,2,3};

// ---------------- CG coefficient (Racah formula, double) ------------------------
__device__ double dfact(int n) { double r = 1.0; for (int i = 2; i <= n; ++i) r *= (double)i; return r; }

__device__ double cg_coeff(int l1, int m1, int l2, int m2, int l3, int m3) {
  if (m3 != m1 + m2) return 0.0;
  double pref = sqrt((2.0 * l3 + 1.0) * dfact(l3 + l1 - l2) * dfact(l3 - l1 + l2)
                     * dfact(l1 + l2 - l3) / dfact(l1 + l2 + l3 + 1));
  pref *= sqrt(dfact(l3 + m3) * dfact(l3 - m3) * dfact(l1 - m1) * dfact(l1 + m1)
               * dfact(l2 - m2) * dfact(l2 + m2));
  double s = 0.0;
  for (int k = 0; k <= l1 + l2 - l3; ++k) {
    int d0 = k, d1 = l1 + l2 - l3 - k, d2 = l1 - m1 - k, d3 = l2 + m2 - k;
    int d4 = l3 - l2 + m1 + k, d5 = l3 - l1 - m2 + k;
    if (d0 < 0 || d1 < 0 || d2 < 0 || d3 < 0 || d4 < 0 || d5 < 0) continue;
    double den = dfact(d0) * dfact(d1) * dfact(d2) * dfact(d3) * dfact(d4) * dfact(d5);
    s += ((k & 1) ? -1.0 : 1.0) / den;
  }
  return pref * s;
}

// ---------------- fused prologue: U->bf16, W^T->bf16, CG table ------------------
__global__ __launch_bounds__(256) void prep(
    const float* __restrict__ u0, const float* __restrict__ u1,
    const float* __restrict__ u2, const float* __restrict__ u3,
    const float* __restrict__ w0, const float* __restrict__ w1,
    const float* __restrict__ w2, const float* __restrict__ w3,
    __bf16* __restrict__ Ubf, __bf16* __restrict__ Wt, float* __restrict__ cg) {
  const int bid = blockIdx.x, tid = threadIdx.x;
  if (bid < 2176) {
    long i = (long)bid * 256 + tid;
    const long b1 = 65536, b2 = 212992, b3 = 393216;
    const float* src; long s;
    if (i < b1)      { src = u0; s = i; }
    else if (i < b2) { src = u1; s = i - b1; }
    else if (i < b3) { src = u2; s = i - b2; }
    else             { src = u3; s = i - b3; }
    float4 v = ((const float4*)src)[s];
    bf16x4 o;
    o[0] = (__bf16)v.x; o[1] = (__bf16)v.y; o[2] = (__bf16)v.z; o[3] = (__bf16)v.w;
    ((bf16x4*)Ubf)[i] = o;
  } else if (bid < 3200) {
    int b = bid - 2176;
    int l = b >> 8, j = b & 255;
    const float* W = (l == 0) ? w0 : (l == 1) ? w1 : (l == 2) ? w2 : w3;
    Wt[((long)l << 16) + (j << 8) + tid] = (__bf16)W[(tid << 8) + j];
  } else {
    int idx = (bid - 3200) * 256 + tid;
    if (idx < 34 * 49) {
      int gp = idx / 49, r = idx % 49;
      int m1i = r / 7, m2i = r % 7;
      int l3 = GP_L[gp], l1 = GP_L1[gp], l2 = GP_L2[gp];
      float v = 0.f;
      if (m1i <= 2 * l1 && m2i <= 2 * l2) {
        int m1 = m1i - l1, m2 = m2i - l2, m3 = m1 + m2;
        if (m3 >= -l3 && m3 <= l3) v = (float)cg_coeff(l1, m1, l2, m2, l3, m3);
      }
      cg[idx] = v;
    }
  }
}

// ---------------- UW GEMM body (per-block, 128x128 tile) ------------------------
struct GemmDesc {
  const __bf16* A[4];
  const __bf16* B[4];
  __bf16*       C[4];
  int start[4];
  int lmap[4];
  int Kd[4];
  int Nc[4];
};

__device__ __forceinline__ void gload_lds16(const void* g, void* l) {
  __builtin_amdgcn_global_load_lds((const __attribute__((address_space(1))) void*)g,
                                   (__attribute__((address_space(3))) void*)l, 16, 0, 0);
}

__device__ void uw_body(const GemmDesc& d, int bid, char* sm) {
  const int tid = threadIdx.x;
  int seg = 0;
  if (bid >= d.start[1]) seg = 1;
  if (bid >= d.start[2]) seg = 2;
  if (bid >= d.start[3]) seg = 3;
  const int l = d.lmap[seg];
  const int rel = bid - d.start[seg];
  const int Kd = d.Kd[l], Nc = d.Nc[l];
  const int nTN = Nc >> 7;
  const int tM = rel / nTN, tN = rel % nTN;

  const int lane = tid & 63, wave = tid >> 6;
  const int wm = (wave >> 1) << 6, wn = (wave & 1) << 6;
  const int lr = lane & 15, lk = (lane >> 4) << 3;

  f32x4 acc[4][4] = {};

  const int r32 = tid >> 3;
  const int sl = ((tid & 7) ^ (r32 & 7)) << 3;
  const __bf16* Ag = d.A[l] + (long)(tM * 128 + r32) * Kd + sl;
  const __bf16* Bg = d.B[l] + (long)(tN * 128 + r32) * Kd + sl;
  char* AsB = sm;
  char* BsB = sm + 16384;

  for (int kt = 0; kt < Kd; kt += 64) {
#pragma unroll
    for (int i = 0; i < 4; ++i) {
      gload_lds16(Ag + (long)i * 32 * Kd + kt, AsB + i * 4096 + tid * 16);
      gload_lds16(Bg + (long)i * 32 * Kd + kt, BsB + i * 4096 + tid * 16);
    }
    __syncthreads();

#pragma unroll
    for (int kk = 0; kk < 64; kk += 32) {
      bf16x8 af[4], bq[4];
#pragma unroll
      for (int mi = 0; mi < 4; ++mi)
        af[mi] = *(const bf16x8*)(AsB + ((wm + mi * 16 + lr) << 7)
                                      + ((((kk + lk) << 1)) ^ ((lr & 7) << 4)));
#pragma unroll
      for (int ni = 0; ni < 4; ++ni)
        bq[ni] = *(const bf16x8*)(BsB + ((wn + ni * 16 + lr) << 7)
                                      + ((((kk + lk) << 1)) ^ ((lr & 7) << 4)));
#pragma unroll
      for (int mi = 0; mi < 4; ++mi)
#pragma unroll
        for (int ni = 0; ni < 4; ++ni)
          acc[mi][ni] = __builtin_amdgcn_mfma_f32_16x16x32_bf16(af[mi], bq[ni], acc[mi][ni], 0, 0, 0);
    }
    __syncthreads();
  }

  const long col0 = (long)tN * 128 + wn + lr;
  const long row0 = (long)tM * 128 + wm + ((lane >> 4) << 2);
#pragma unroll
  for (int mi = 0; mi < 4; ++mi)
#pragma unroll
    for (int j = 0; j < 4; ++j) {
      long r = row0 + mi * 16 + j;
      long base = r * (long)Nc + col0;
#pragma unroll
      for (int ni = 0; ni < 4; ++ni)
        d.C[l][base + ni * 16] = (__bf16)acc[mi][ni][j];
    }
}

// ---------------- TP body: one f-read -> all 34 paths ---------------------------
#define TPW2(LV, DST, CIN, GOFF, P, L1V, L2V)                                    \
  { f32x2 tp[2 * (LV) + 1];                                                      \
    _Pragma("unroll") for (int m = 0; m <= 2 * (LV); ++m) { tp[m][0] = 0.f; tp[m][1] = 0.f; } \
    const float* cgt = cg + ((GOFF) + (P)) * 49;                                 \
    _Pragma("unroll") for (int a = 0; a <= 2 * (L1V); ++a)                       \
      _Pragma("unroll") for (int b = 0; b <= 2 * (L2V); ++b) {                   \
        const int m = a + b - ((L1V) + (L2V) - (LV));                            \
        if (m >= 0 && m <= 2 * (LV)) {                                           \
          float c = cgt[a * 7 + b];                                              \
          tp[m][0] = fmaf(c, v1[CUM[L1V] + a][0] * v2[CUM[L2V] + b][0], tp[m][0]); \
          tp[m][1] = fmaf(c, v1[CUM[L1V] + a][1] * v2[CUM[L2V] + b][1], tp[m][1]); \
        } }                                                                      \
    __bf16* o = (DST) + (n * (2 * (LV) + 1)) * (CIN) + (P) * 256 + k2;           \
    _Pragma("unroll") for (int m = 0; m <= 2 * (LV); ++m) {                      \
      bf16x2 ov; ov[0] = (__bf16)tp[m][0]; ov[1] = (__bf16)tp[m][1];             \
      *(bf16x2*)(o + (long)m * (CIN)) = ov; } }

template <int LMASK>
__device__ void tp_body(
    const float* __restrict__ f10, const float* __restrict__ f11,
    const float* __restrict__ f12, const float* __restrict__ f13,
    const float* __restrict__ f20, const float* __restrict__ f21,
    const float* __restrict__ f22, const float* __restrict__ f23,
    const float* __restrict__ cg,
    __bf16* __restrict__ A0, __bf16* __restrict__ A1,
    __bf16* __restrict__ A2, __bf16* __restrict__ A3, int bid) {
  const int tid = threadIdx.x;
  const long n = (long)bid * 2 + (tid >> 7);
  const int k2 = (tid & 127) << 1;
  constexpr int CUM[4] = {0, 1, 4, 9};
  const float* f1s[4] = {f10, f11, f12, f13};
  const float* f2s[4] = {f20, f21, f22, f23};

  f32x2 v1[16], v2[16];
#pragma unroll
  for (int l1 = 0; l1 < 4; ++l1) {
    const float* p1 = f1s[l1] + (n * (2 * l1 + 1)) * 256 + k2;
    const float* p2 = f2s[l1] + (n * (2 * l1 + 1)) * 256 + k2;
#pragma unroll
    for (int a = 0; a <= 2 * l1; ++a) {
      v1[CUM[l1] + a] = *(const f32x2*)(p1 + (long)a * 256);
      v2[CUM[l1] + a] = *(const f32x2*)(p2 + (long)a * 256);
    }
  }

  if constexpr (LMASK & 1) {
    TPW2(0, A0, 1024, 0, 0, 0, 0)  TPW2(0, A0, 1024, 0, 1, 1, 1)
    TPW2(0, A0, 1024, 0, 2, 2, 2)  TPW2(0, A0, 1024, 0, 3, 3, 3)
  }
  if constexpr (LMASK & 2) {
    TPW2(1, A1, 2304, 4, 0, 0, 1)  TPW2(1, A1, 2304, 4, 1, 1, 0)
    TPW2(1, A1, 2304, 4, 2, 1, 1)  TPW2(1, A1, 2304, 4, 3, 1, 2)
    TPW2(1, A1, 2304, 4, 4, 2, 1)  TPW2(1, A1, 2304, 4, 5, 2, 2)
    TPW2(1, A1, 2304, 4, 6, 2, 3)  TPW2(1, A1, 2304, 4, 7, 3, 2)
    TPW2(1, A1, 2304, 4, 8, 3, 3)
  }
  if constexpr (LMASK & 4) {
    TPW2(2, A2, 2816, 13, 0, 0, 2)  TPW2(2, A2, 2816, 13, 1, 1, 1)
    TPW2(2, A2, 2816, 13, 2, 1, 2)  TPW2(2, A2, 2816, 13, 3, 1, 3)
    TPW2(2, A2, 2816, 13, 4, 2, 0)  TPW2(2, A2, 2816, 13, 5, 2, 1)
    TPW2(2, A2, 2816, 13, 6, 2, 2)  TPW2(2, A2, 2816, 13, 7, 2, 3)
    TPW2(2, A2, 2816, 13, 8, 3, 1)  TPW2(2, A2, 2816, 13, 9, 3, 2)
    TPW2(2, A2, 2816, 13, 10, 3, 3)
  }
  if constexpr (LMASK & 8) {
    TPW2(3, A3, 2560, 24, 0, 0, 3)  TPW2(3, A3, 2560, 24, 1, 1, 2)
    TPW2(3, A3, 2560, 24, 2, 1, 3)  TPW2(3, A3, 2560, 24, 3, 2, 1)
    TPW2(3, A3, 2560, 24, 4, 2, 2)  TPW2(3, A3, 2560, 24, 5, 2, 3)
    TPW2(3, A3, 2560, 24, 6, 3, 0)  TPW2(3, A3, 2560, 24, 7, 3, 1)
    TPW2(3, A3, 2560, 24, 8, 3, 2)  TPW2(3, A3, 2560, 24, 9, 3, 3)
  }
}

// ---------------- combined TP + UW launch (independent work, one dispatch) ------
template <int LMASK>
__global__ __launch_bounds__(256) void tp_uw(
    const float* __restrict__ f10, const float* __restrict__ f11,
    const float* __restrict__ f12, const float* __restrict__ f13,
    const float* __restrict__ f20, const float* __restrict__ f21,
    const float* __restrict__ f22, const float* __restrict__ f23,
    const float* __restrict__ cg,
    __bf16* __restrict__ A0, __bf16* __restrict__ A1,
    __bf16* __restrict__ A2, __bf16* __restrict__ A3,
    GemmDesc gd, int nUW) {
  __shared__ __align__(16) char sm[32768];
  const int bid = (int)blockIdx.x;
  if (bid < nUW) {
    uw_body(gd, bid, sm);
  } else if constexpr (LMASK != 0) {
    tp_body<LMASK>(f10, f11, f12, f13, f20, f21, f22, f23, cg,
                   A0, A1, A2, A3, bid - nUW);
  }
}

// ---------------- main GEMM: 32x256 tiles, 4 blocks/CU, single-buffer ----------
struct MainDesc {
  const __bf16* A[4];
  const __bf16* B[4];
  float*        C[4];
  const float*  R[4];
  int start[4];
  int lmap[4];
  int cin4[4];
};

__global__ __launch_bounds__(256) void gemm_main(MainDesc d) {
  // A 4KB @0 + B 32KB @4096 = 36 KB single-stage -> 4 blocks/CU co-resident
  __shared__ __align__(16) char sm[36864];
  const int tid = threadIdx.x;
  int bid;
  {  // chunked XCD swizzle (gridDim.x divisible by 8)
    const int cpx = gridDim.x >> 3;
    bid = ((int)blockIdx.x & 7) * cpx + ((int)blockIdx.x >> 3);
  }
  int seg = 0;
  if (bid >= d.start[1]) seg = 1;
  if (bid >= d.start[2]) seg = 2;
  if (bid >= d.start[3]) seg = 3;
  const int l = d.lmap[seg];
  const int tM = bid - d.start[seg];
  const int cin = d.cin4[l];

  const __bf16* __restrict__ Aseg = d.A[l] + (long)tM * 32 * cin;
  const __bf16* __restrict__ Bseg = d.B[l];

  const int r32 = tid >> 3;                        // 0..31
  const int sx = ((tid & 7) ^ (r32 & 7)) << 3;     // inverse-swizzled global k-slot

  const int lane = tid & 63, wave = tid >> 6;
  const int wn = wave << 6;                        // 0/64/128/192
  const int lr = lane & 15, lkb = (lane >> 4) << 3;

  f32x4 acc[2][4] = {};

  for (int kt = 0; kt < cin; kt += 64) {
    // stage: A 32x64 (1 load/thread), B 256x64 (8 loads/thread)
    gload_lds16(Aseg + (long)r32 * cin + kt + sx, sm + tid * 16);
#pragma unroll
    for (int i = 0; i < 8; ++i)
      gload_lds16(Bseg + (long)(i * 32 + r32) * cin + kt + sx,
                  sm + 4096 + i * 4096 + tid * 16);
    __syncthreads();

#pragma unroll
    for (int kk = 0; kk < 64; kk += 32) {
      bf16x8 af[2], bq[4];
#pragma unroll
      for (int mi = 0; mi < 2; ++mi) {
        const int row = mi * 16 + lr;
        af[mi] = *(const bf16x8*)(sm + row * 128 + ((((kk + lkb) << 1)) ^ ((row & 7) << 4)));
      }
#pragma unroll
      for (int ni = 0; ni < 4; ++ni) {
        const int row = wn + ni * 16 + lr;
        bq[ni] = *(const bf16x8*)(sm + 4096 + row * 128 + ((((kk + lkb) << 1)) ^ ((row & 7) << 4)));
      }
#pragma unroll
      for (int mi = 0; mi < 2; ++mi)
#pragma unroll
        for (int ni = 0; ni < 4; ++ni)
          acc[mi][ni] = __builtin_amdgcn_mfma_f32_16x16x32_bf16(af[mi], bq[ni], acc[mi][ni], 0, 0, 0);
    }
    __syncthreads();
  }

  // epilogue: C = acc + resid (M_l divisible by 32 -> no guards)
  float* __restrict__ Cout = d.C[l];
  const float* __restrict__ Resid = d.R[l];
  const int rb = (lane >> 4) << 2;
#pragma unroll
  for (int mi = 0; mi < 2; ++mi)
#pragma unroll
    for (int j = 0; j < 4; ++j) {
      const long row = (long)tM * 32 + mi * 16 + rb + j;
      const long base = row * 256 + wn + lr;
#pragma unroll
      for (int ni = 0; ni < 4; ++ni)
        Cout[base + ni * 16] = acc[mi][ni][j] + Resid[base + ni * 16];
    }
}

// ---------------- launch ---------------------------------------------------------
extern "C" void kernel_launch(void* const* d_in, const int* in_sizes, int n_in,
                              void* d_out, int out_size, void* d_ws, size_t ws_size,
                              hipStream_t stream) {
  const float* F1[4], * F2[4], * Uin[4], * Win[4];
  for (int l = 0; l < 4; ++l) {
    F1[l]  = (const float*)d_in[4 * l + 0];
    F2[l]  = (const float*)d_in[4 * l + 1];
    Uin[l] = (const float*)d_in[4 * l + 2];
    Win[l] = (const float*)d_in[4 * l + 3];
  }
  static const int  cin_[4]  = {1024, 2304, 2816, 2560};
  static const int  cum_[4]  = {0, 1024, 3328, 6144};
  static const long moff_[4] = {0, 524288, 2097152, 4718592};
  static const int  nBLK_[4] = {64, 192, 320, 448};   // M_l / 32
  static const long asz_[4]  = {4194304L, 28311552L, 57671680L, 73400320L}; // bytes

  char* ws = (char*)d_ws;
  float*  cg   = (float*)ws;                        // 6664 B
  __bf16* Ubf  = (__bf16*)(ws + 8192);              // 4,456,448 B
  __bf16* Wtbf = (__bf16*)(ws + 8192 + 4456448);    // 524,288 B
  __bf16* UWt  = (__bf16*)(ws + 5242880);           // 4,456,448 B
  const long ABASE = 10485760;
  const bool big = ws_size >= (size_t)(ABASE + asz_[0] + asz_[1] + asz_[2] + asz_[3]);

  __bf16* Ab[4];
  if (big) {
    long off = ABASE;
    for (int l = 0; l < 4; ++l) { Ab[l] = (__bf16*)(ws + off); off += asz_[l]; }
  } else {
    for (int l = 0; l < 4; ++l) Ab[l] = (__bf16*)(ws + ABASE);
  }

  hipLaunchKernelGGL(prep, dim3(3207), dim3(256), 0, stream,
                     Uin[0], Uin[1], Uin[2], Uin[3],
                     Win[0], Win[1], Win[2], Win[3], Ubf, Wtbf, cg);

  GemmDesc gd;
  {
    int starts[4] = {0, 40, 84, 120};   // order l3,l2,l1,l0
    int lmap[4]   = {3, 2, 1, 0};
    for (int s = 0; s < 4; ++s) { gd.start[s] = starts[s]; gd.lmap[s] = lmap[s]; }
    for (int l = 0; l < 4; ++l) {
      gd.A[l] = Wtbf + (long)l * 65536;
      gd.B[l] = Ubf + (long)cum_[l] * 256;
      gd.C[l] = UWt + (long)cum_[l] * 256;
      gd.Kd[l] = 256;
      gd.Nc[l] = cin_[l];
    }
  }

  if (big) {
    // one launch: 136 UW-GEMM blocks + 1024 TP blocks (independent, overlap)
    hipLaunchKernelGGL((tp_uw<15>), dim3(1160), dim3(256), 0, stream,
                       F1[0], F1[1], F1[2], F1[3], F2[0], F2[1], F2[2], F2[3],
                       cg, Ab[0], Ab[1], Ab[2], Ab[3], gd, 136);
    MainDesc d;
    int starts[4] = {0, 448, 768, 960};   // l3(448) l2(320) l1(192) l0(64)
    int lmap[4]   = {3, 2, 1, 0};
    for (int s = 0; s < 4; ++s) { d.start[s] = starts[s]; d.lmap[s] = lmap[s]; }
    for (int l = 0; l < 4; ++l) {
      d.A[l] = Ab[l];
      d.B[l] = UWt + (long)cum_[l] * 256;
      d.C[l] = (float*)d_out + moff_[l];
      d.R[l] = F1[l];
      d.cin4[l] = cin_[l];
    }
    hipLaunchKernelGGL(gemm_main, dim3(1024), dim3(256), 0, stream, d);
  } else {
    // fallback: UW first, then per-l TP + main GEMM reusing one A buffer
    hipLaunchKernelGGL((tp_uw<0>), dim3(136), dim3(256), 0, stream,
                       F1[0], F1[1], F1[2], F1[3], F2[0], F2[1], F2[2], F2[3],
                       cg, Ab[0], Ab[1], Ab[2], Ab[3], gd, 136);
    for (int l = 0; l < 4; ++l) {
      switch (l) {
        case 0: hipLaunchKernelGGL((tp_uw<1>), dim3(1024), dim3(256), 0, stream,
                  F1[0],F1[1],F1[2],F1[3], F2[0],F2[1],F2[2],F2[3], cg,
                  Ab[0],Ab[1],Ab[2],Ab[3], gd, 0); break;
        case 1: hipLaunchKernelGGL((tp_uw<2>), dim3(1024), dim3(256), 0, stream,
                  F1[0],F1[1],F1[2],F1[3], F2[0],F2[1],F2[2],F2[3], cg,
                  Ab[0],Ab[1],Ab[2],Ab[3], gd, 0); break;
        case 2: hipLaunchKernelGGL((tp_uw<4>), dim3(1024), dim3(256), 0, stream,
                  F1[0],F1[1],F1[2],F1[3], F2[0],F2[1],F2[2],F2[3], cg,
                  Ab[0],Ab[1],Ab[2],Ab[3], gd, 0); break;
        case 3: hipLaunchKernelGGL((tp_uw<8>), dim3(1024), dim3(256), 0, stream,
                  F1[0],F1[1],F1[2],F1[3], F2[0],F2[1],F2[2],F2[3], cg,
                  Ab[0],Ab[1],Ab[2],Ab[3], gd, 0); break;
      }
      MainDesc d;
      for (int s = 0; s < 4; ++s) {
        d.start[s] = (s == 0) ? 0 : 0x7fffffff;
        d.lmap[s] = l;
      }
      for (int ll = 0; ll < 4; ++ll) {
        d.A[ll] = Ab[l];
        d.B[ll] = UWt + (long)cum_[l] * 256;
        d.C[ll] = (float*)d_out + moff_[l];
        d.R[ll] = F1[l];
        d.cin4[ll] = cin_[l];
      }
      hipLaunchKernelGGL(gemm_main, dim3(nBLK_[l]), dim3(256), 0, stream, d);
    }
  }
  (void)in_sizes; (void)n_in; (void)out_size; (void)ws_size;
}

// Round 13
// 125.503 us; speedup vs baseline: 1.3877x; 1.3877x over previous
//
#include <hip/hip_runtime.h>
#include <math.h>

typedef __attribute__((ext_vector_type(4))) float f32x4;
typedef __attribute__((ext_vector_type(2))) float f32x2;
typedef __attribute__((ext_vector_type(8))) __bf16 bf16x8;
typedef __attribute__((ext_vector_type(4))) __bf16 bf16x4;
typedef __attribute__((ext_vector_type(2))) __bf16 bf16x2;

// ---------------- path tables (order matches Python PATHS enumeration) ----------
__device__ __constant__ int GP_L[34]  = {0,0,0,0, 1,1,1,1,1,1,1,1,1, 2,2,2,2,2,2,2,2,2,2,2, 3,3,3,3,3,3,3,3,3,3};
__device__ __constant__ int GP_L1[34] = {0,1,2,3, 0,1,1,1,2,2,2,3,3, 0,1,1,1,2,2,2,2,3,3,3, 0,1,1,2,2,2,3,3,3,3};
__device__ __constant__ int GP_L2[34] = {0,1,2,3, 1,0,1,2,1,2,3,2,3, 2,1,2,3,0,1,2,3,1,2,3, 3,2,3,1,2,3,0,1,2,3};

// ---------------- CG coefficient (Racah formula, double) ------------------------
__device__ double dfact(int n) { double r = 1.0; for (int i = 2; i <= n; ++i) r *= (double)i; return r; }

__device__ double cg_coeff(int l1, int m1, int l2, int m2, int l3, int m3) {
  if (m3 != m1 + m2) return 0.0;
  double pref = sqrt((2.0 * l3 + 1.0) * dfact(l3 + l1 - l2) * dfact(l3 - l1 + l2)
                     * dfact(l1 + l2 - l3) / dfact(l1 + l2 + l3 + 1));
  pref *= sqrt(dfact(l3 + m3) * dfact(l3 - m3) * dfact(l1 - m1) * dfact(l1 + m1)
               * dfact(l2 - m2) * dfact(l2 + m2));
  double s = 0.0;
  for (int k = 0; k <= l1 + l2 - l3; ++k) {
    int d0 = k, d1 = l1 + l2 - l3 - k, d2 = l1 - m1 - k, d3 = l2 + m2 - k;
    int d4 = l3 - l2 + m1 + k, d5 = l3 - l1 - m2 + k;
    if (d0 < 0 || d1 < 0 || d2 < 0 || d3 < 0 || d4 < 0 || d5 < 0) continue;
    double den = dfact(d0) * dfact(d1) * dfact(d2) * dfact(d3) * dfact(d4) * dfact(d5);
    s += ((k & 1) ? -1.0 : 1.0) / den;
  }
  return pref * s;
}

// ---------------- fused prologue: U->bf16, W^T->bf16, CG table ------------------
__global__ __launch_bounds__(256) void prep(
    const float* __restrict__ u0, const float* __restrict__ u1,
    const float* __restrict__ u2, const float* __restrict__ u3,
    const float* __restrict__ w0, const float* __restrict__ w1,
    const float* __restrict__ w2, const float* __restrict__ w3,
    __bf16* __restrict__ Ubf, __bf16* __restrict__ Wt, float* __restrict__ cg) {
  const int bid = blockIdx.x, tid = threadIdx.x;
  if (bid < 2176) {
    long i = (long)bid * 256 + tid;
    const long b1 = 65536, b2 = 212992, b3 = 393216;
    const float* src; long s;
    if (i < b1)      { src = u0; s = i; }
    else if (i < b2) { src = u1; s = i - b1; }
    else if (i < b3) { src = u2; s = i - b2; }
    else             { src = u3; s = i - b3; }
    float4 v = ((const float4*)src)[s];
    bf16x4 o;
    o[0] = (__bf16)v.x; o[1] = (__bf16)v.y; o[2] = (__bf16)v.z; o[3] = (__bf16)v.w;
    ((bf16x4*)Ubf)[i] = o;
  } else if (bid < 3200) {
    int b = bid - 2176;
    int l = b >> 8, j = b & 255;
    const float* W = (l == 0) ? w0 : (l == 1) ? w1 : (l == 2) ? w2 : w3;
    Wt[((long)l << 16) + (j << 8) + tid] = (__bf16)W[(tid << 8) + j];
  } else {
    int idx = (bid - 3200) * 256 + tid;
    if (idx < 34 * 49) {
      int gp = idx / 49, r = idx % 49;
      int m1i = r / 7, m2i = r % 7;
      int l3 = GP_L[gp], l1 = GP_L1[gp], l2 = GP_L2[gp];
      float v = 0.f;
      if (m1i <= 2 * l1 && m2i <= 2 * l2) {
        int m1 = m1i - l1, m2 = m2i - l2, m3 = m1 + m2;
        if (m3 >= -l3 && m3 <= l3) v = (float)cg_coeff(l1, m1, l2, m2, l3, m3);
      }
      cg[idx] = v;
    }
  }
}

// ---------------- UW GEMM body (per-block, 128x128 tile) ------------------------
struct GemmDesc {
  const __bf16* A[4];
  const __bf16* B[4];
  __bf16*       C[4];
  int start[4];
  int lmap[4];
  int Kd[4];
  int Nc[4];
};

__device__ __forceinline__ void gload_lds16(const void* g, void* l) {
  __builtin_amdgcn_global_load_lds((const __attribute__((address_space(1))) void*)g,
                                   (__attribute__((address_space(3))) void*)l, 16, 0, 0);
}

__device__ void uw_body(const GemmDesc& d, int bid, char* sm) {
  const int tid = threadIdx.x;
  int seg = 0;
  if (bid >= d.start[1]) seg = 1;
  if (bid >= d.start[2]) seg = 2;
  if (bid >= d.start[3]) seg = 3;
  const int l = d.lmap[seg];
  const int rel = bid - d.start[seg];
  const int Kd = d.Kd[l], Nc = d.Nc[l];
  const int nTN = Nc >> 7;
  const int tM = rel / nTN, tN = rel % nTN;

  const int lane = tid & 63, wave = tid >> 6;
  const int wm = (wave >> 1) << 6, wn = (wave & 1) << 6;
  const int lr = lane & 15, lk = (lane >> 4) << 3;

  f32x4 acc[4][4] = {};

  const int r32 = tid >> 3;
  const int sl = ((tid & 7) ^ (r32 & 7)) << 3;
  const __bf16* Ag = d.A[l] + (long)(tM * 128 + r32) * Kd + sl;
  const __bf16* Bg = d.B[l] + (long)(tN * 128 + r32) * Kd + sl;
  char* AsB = sm;
  char* BsB = sm + 16384;

  for (int kt = 0; kt < Kd; kt += 64) {
#pragma unroll
    for (int i = 0; i < 4; ++i) {
      gload_lds16(Ag + (long)i * 32 * Kd + kt, AsB + i * 4096 + tid * 16);
      gload_lds16(Bg + (long)i * 32 * Kd + kt, BsB + i * 4096 + tid * 16);
    }
    __syncthreads();

#pragma unroll
    for (int kk = 0; kk < 64; kk += 32) {
      bf16x8 af[4], bq[4];
#pragma unroll
      for (int mi = 0; mi < 4; ++mi)
        af[mi] = *(const bf16x8*)(AsB + ((wm + mi * 16 + lr) << 7)
                                      + ((((kk + lk) << 1)) ^ ((lr & 7) << 4)));
#pragma unroll
      for (int ni = 0; ni < 4; ++ni)
        bq[ni] = *(const bf16x8*)(BsB + ((wn + ni * 16 + lr) << 7)
                                      + ((((kk + lk) << 1)) ^ ((lr & 7) << 4)));
#pragma unroll
      for (int mi = 0; mi < 4; ++mi)
#pragma unroll
        for (int ni = 0; ni < 4; ++ni)
          acc[mi][ni] = __builtin_amdgcn_mfma_f32_16x16x32_bf16(af[mi], bq[ni], acc[mi][ni], 0, 0, 0);
    }
    __syncthreads();
  }

  const long col0 = (long)tN * 128 + wn + lr;
  const long row0 = (long)tM * 128 + wm + ((lane >> 4) << 2);
#pragma unroll
  for (int mi = 0; mi < 4; ++mi)
#pragma unroll
    for (int j = 0; j < 4; ++j) {
      long r = row0 + mi * 16 + j;
      long base = r * (long)Nc + col0;
#pragma unroll
      for (int ni = 0; ni < 4; ++ni)
        d.C[l][base + ni * 16] = (__bf16)acc[mi][ni][j];
    }
}

// ---------------- TP body: one f-read -> all 34 paths ---------------------------
#define TPW2(LV, DST, CIN, GOFF, P, L1V, L2V)                                    \
  { f32x2 tp[2 * (LV) + 1];                                                      \
    _Pragma("unroll") for (int m = 0; m <= 2 * (LV); ++m) { tp[m][0] = 0.f; tp[m][1] = 0.f; } \
    const float* cgt = cg + ((GOFF) + (P)) * 49;                                 \
    _Pragma("unroll") for (int a = 0; a <= 2 * (L1V); ++a)                       \
      _Pragma("unroll") for (int b = 0; b <= 2 * (L2V); ++b) {                   \
        const int m = a + b - ((L1V) + (L2V) - (LV));                            \
        if (m >= 0 && m <= 2 * (LV)) {                                           \
          float c = cgt[a * 7 + b];                                              \
          tp[m][0] = fmaf(c, v1[CUM[L1V] + a][0] * v2[CUM[L2V] + b][0], tp[m][0]); \
          tp[m][1] = fmaf(c, v1[CUM[L1V] + a][1] * v2[CUM[L2V] + b][1], tp[m][1]); \
        } }                                                                      \
    __bf16* o = (DST) + (n * (2 * (LV) + 1)) * (CIN) + (P) * 256 + k2;           \
    _Pragma("unroll") for (int m = 0; m <= 2 * (LV); ++m) {                      \
      bf16x2 ov; ov[0] = (__bf16)tp[m][0]; ov[1] = (__bf16)tp[m][1];             \
      *(bf16x2*)(o + (long)m * (CIN)) = ov; } }

template <int LMASK>
__device__ void tp_body(
    const float* __restrict__ f10, const float* __restrict__ f11,
    const float* __restrict__ f12, const float* __restrict__ f13,
    const float* __restrict__ f20, const float* __restrict__ f21,
    const float* __restrict__ f22, const float* __restrict__ f23,
    const float* __restrict__ cg,
    __bf16* __restrict__ A0, __bf16* __restrict__ A1,
    __bf16* __restrict__ A2, __bf16* __restrict__ A3, int bid) {
  const int tid = threadIdx.x;
  const long n = (long)bid * 2 + (tid >> 7);
  const int k2 = (tid & 127) << 1;
  constexpr int CUM[4] = {0, 1, 4, 9};
  const float* f1s[4] = {f10, f11, f12, f13};
  const float* f2s[4] = {f20, f21, f22, f23};

  f32x2 v1[16], v2[16];
#pragma unroll
  for (int l1 = 0; l1 < 4; ++l1) {
    const float* p1 = f1s[l1] + (n * (2 * l1 + 1)) * 256 + k2;
    const float* p2 = f2s[l1] + (n * (2 * l1 + 1)) * 256 + k2;
#pragma unroll
    for (int a = 0; a <= 2 * l1; ++a) {
      v1[CUM[l1] + a] = *(const f32x2*)(p1 + (long)a * 256);
      v2[CUM[l1] + a] = *(const f32x2*)(p2 + (long)a * 256);
    }
  }

  if constexpr (LMASK & 1) {
    TPW2(0, A0, 1024, 0, 0, 0, 0)  TPW2(0, A0, 1024, 0, 1, 1, 1)
    TPW2(0, A0, 1024, 0, 2, 2, 2)  TPW2(0, A0, 1024, 0, 3, 3, 3)
  }
  if constexpr (LMASK & 2) {
    TPW2(1, A1, 2304, 4, 0, 0, 1)  TPW2(1, A1, 2304, 4, 1, 1, 0)
    TPW2(1, A1, 2304, 4, 2, 1, 1)  TPW2(1, A1, 2304, 4, 3, 1, 2)
    TPW2(1, A1, 2304, 4, 4, 2, 1)  TPW2(1, A1, 2304, 4, 5, 2, 2)
    TPW2(1, A1, 2304, 4, 6, 2, 3)  TPW2(1, A1, 2304, 4, 7, 3, 2)
    TPW2(1, A1, 2304, 4, 8, 3, 3)
  }
  if constexpr (LMASK & 4) {
    TPW2(2, A2, 2816, 13, 0, 0, 2)  TPW2(2, A2, 2816, 13, 1, 1, 1)
    TPW2(2, A2, 2816, 13, 2, 1, 2)  TPW2(2, A2, 2816, 13, 3, 1, 3)
    TPW2(2, A2, 2816, 13, 4, 2, 0)  TPW2(2, A2, 2816, 13, 5, 2, 1)
    TPW2(2, A2, 2816, 13, 6, 2, 2)  TPW2(2, A2, 2816, 13, 7, 2, 3)
    TPW2(2, A2, 2816, 13, 8, 3, 1)  TPW2(2, A2, 2816, 13, 9, 3, 2)
    TPW2(2, A2, 2816, 13, 10, 3, 3)
  }
  if constexpr (LMASK & 8) {
    TPW2(3, A3, 2560, 24, 0, 0, 3)  TPW2(3, A3, 2560, 24, 1, 1, 2)
    TPW2(3, A3, 2560, 24, 2, 1, 3)  TPW2(3, A3, 2560, 24, 3, 2, 1)
    TPW2(3, A3, 2560, 24, 4, 2, 2)  TPW2(3, A3, 2560, 24, 5, 2, 3)
    TPW2(3, A3, 2560, 24, 6, 3, 0)  TPW2(3, A3, 2560, 24, 7, 3, 1)
    TPW2(3, A3, 2560, 24, 8, 3, 2)  TPW2(3, A3, 2560, 24, 9, 3, 3)
  }
}

// ---------------- combined TP + UW launch (independent work, one dispatch) ------
template <int LMASK>
__global__ __launch_bounds__(256) void tp_uw(
    const float* __restrict__ f10, const float* __restrict__ f11,
    const float* __restrict__ f12, const float* __restrict__ f13,
    const float* __restrict__ f20, const float* __restrict__ f21,
    const float* __restrict__ f22, const float* __restrict__ f23,
    const float* __restrict__ cg,
    __bf16* __restrict__ A0, __bf16* __restrict__ A1,
    __bf16* __restrict__ A2, __bf16* __restrict__ A3,
    GemmDesc gd, int nUW) {
  __shared__ __align__(16) char sm[32768];
  const int bid = (int)blockIdx.x;
  if (bid < nUW) {
    uw_body(gd, bid, sm);
  } else if constexpr (LMASK != 0) {
    tp_body<LMASK>(f10, f11, f12, f13, f20, f21, f22, f23, cg,
                   A0, A1, A2, A3, bid - nUW);
  }
}

// ---------------- main GEMM: 256x128 tile, 8 waves, 3-stage per-phase pipeline --
struct MainDesc {
  const __bf16* A[4];
  const __bf16* B[4];
  float*        C[4];
  const float*  R[4];
  int start[4];
  int lmap[4];
  int cin4[4];
};

__global__ __launch_bounds__(512) void gemm_main(MainDesc d) {
  // 3 stages x (A 32KB + B 16KB) = 144 KB; 512 thr = 8 waves (wave tile 64x64)
  __shared__ __align__(16) char sm[147456];
  const int tid = threadIdx.x;
  int bid;
  {  // chunked XCD swizzle (gridDim.x divisible by 8)
    const int cpx = gridDim.x >> 3;
    bid = ((int)blockIdx.x & 7) * cpx + ((int)blockIdx.x >> 3);
  }
  int seg = 0;
  if (bid >= d.start[1]) seg = 1;
  if (bid >= d.start[2]) seg = 2;
  if (bid >= d.start[3]) seg = 3;
  const int l = d.lmap[seg];
  const int rel = bid - d.start[seg];
  const int tM = rel >> 1, tN = rel & 1;     // tN inner: consecutive bids share A-panel
  const int cin = d.cin4[l];
  const int NT = cin >> 6;                   // BK = 64

  const __bf16* __restrict__ Aseg = d.A[l] + (long)tM * 256 * cin;
  const __bf16* __restrict__ Bseg = d.B[l] + (long)tN * 128 * cin;

  const int srow = tid >> 3;                                  // 0..63
  const int sx = (((tid & 7) ^ ((tid >> 3) & 7)) << 3);       // inverse-swizzled k-slot

  const int lane = tid & 63, wave = tid >> 6;
  const int wm = (wave >> 1) << 6;           // 0/64/128/192 (4 M-rows of waves)
  const int wn = (wave & 1) << 6;            // 0/64        (2 N-cols of waves)
  const int lr = lane & 15, lkb = (lane >> 4) << 3;
  const int xorb = (lr & 7) << 4;
  const int aoff = (wm + lr) << 7;
  const int boff = (wn + lr) << 7;

  f32x4 acc[4][4];
#pragma unroll
  for (int i = 0; i < 4; ++i)
#pragma unroll
    for (int j = 0; j < 4; ++j) { acc[i][j][0]=0.f; acc[i][j][1]=0.f; acc[i][j][2]=0.f; acc[i][j][3]=0.f; }

  // staging: A 256x64 (4 loads/thr), B 128x64 (2 loads/thr); linear LDS dest,
  // inverse-swizzled global k-slot (rule #21). Split 3+3 across the two phases.
#define SG_A3(s, t)                                                              \
  { char* b_ = sm + (s) * 49152; const long kt_ = (long)(t) << 6;                \
    gload_lds16(Aseg + (long)(  0 + srow) * cin + kt_ + sx, b_ +     0 + tid * 16); \
    gload_lds16(Aseg + (long)( 64 + srow) * cin + kt_ + sx, b_ +  8192 + tid * 16); \
    gload_lds16(Aseg + (long)(128 + srow) * cin + kt_ + sx, b_ + 16384 + tid * 16); }
#define SG_REST(s, t)                                                            \
  { char* b_ = sm + (s) * 49152; const long kt_ = (long)(t) << 6;                \
    gload_lds16(Aseg + (long)(192 + srow) * cin + kt_ + sx, b_ + 24576 + tid * 16); \
    gload_lds16(Bseg + (long)(  0 + srow) * cin + kt_ + sx, b_ + 32768 + tid * 16); \
    gload_lds16(Bseg + (long)( 64 + srow) * cin + kt_ + sx, b_ + 40960 + tid * 16); }

  SG_A3(0, 0) SG_REST(0, 0)
  SG_A3(1, 1) SG_REST(1, 1)
  asm volatile("s_waitcnt vmcnt(6)" ::: "memory");   // tile 0 landed
  __builtin_amdgcn_s_barrier();
  __builtin_amdgcn_sched_barrier(0);

  for (int t = 0; t < NT; ++t) {
    const char* Ab = sm + (t % 3) * 49152;
    const char* Bb = Ab + 32768;
    const bool pf = (t + 2 < NT);
    const int ns = (t + 2) % 3;
    bf16x8 af[4], bq[4];

    // ---------- phase 0 (kk = 0) ----------
    {
      const int kb = ((lkb << 1)) ^ xorb;
#pragma unroll
      for (int mi = 0; mi < 4; ++mi) af[mi] = *(const bf16x8*)(Ab + aoff + mi * 2048 + kb);
#pragma unroll
      for (int ni = 0; ni < 4; ++ni) bq[ni] = *(const bf16x8*)(Bb + boff + ni * 2048 + kb);
    }
    if (pf) SG_A3(ns, t + 2)
    __builtin_amdgcn_sched_barrier(0);
    __builtin_amdgcn_s_barrier();
    asm volatile("s_waitcnt lgkmcnt(0)" ::: "memory");
    __builtin_amdgcn_sched_barrier(0);
    __builtin_amdgcn_s_setprio(1);
#pragma unroll
    for (int mi = 0; mi < 4; ++mi)
#pragma unroll
      for (int ni = 0; ni < 4; ++ni)
        acc[mi][ni] = __builtin_amdgcn_mfma_f32_16x16x32_bf16(af[mi], bq[ni], acc[mi][ni], 0, 0, 0);
    __builtin_amdgcn_s_setprio(0);
    __builtin_amdgcn_sched_barrier(0);
    __builtin_amdgcn_s_barrier();
    __builtin_amdgcn_sched_barrier(0);

    // ---------- phase 1 (kk = 32) ----------
    {
      const int kb = (((32 + lkb) << 1)) ^ xorb;
#pragma unroll
      for (int mi = 0; mi < 4; ++mi) af[mi] = *(const bf16x8*)(Ab + aoff + mi * 2048 + kb);
#pragma unroll
      for (int ni = 0; ni < 4; ++ni) bq[ni] = *(const bf16x8*)(Bb + boff + ni * 2048 + kb);
    }
    if (pf) SG_REST(ns, t + 2)
    __builtin_amdgcn_sched_barrier(0);
    __builtin_amdgcn_s_barrier();
    asm volatile("s_waitcnt lgkmcnt(0)" ::: "memory");
    __builtin_amdgcn_sched_barrier(0);
    __builtin_amdgcn_s_setprio(1);
#pragma unroll
    for (int mi = 0; mi < 4; ++mi)
#pragma unroll
      for (int ni = 0; ni < 4; ++ni)
        acc[mi][ni] = __builtin_amdgcn_mfma_f32_16x16x32_bf16(af[mi], bq[ni], acc[mi][ni], 0, 0, 0);
    __builtin_amdgcn_s_setprio(0);
    __builtin_amdgcn_sched_barrier(0);
    // counted wait: ensure tile t+1 landed before its phase-0 ds_reads (after barrier)
    if (t < NT - 2)       asm volatile("s_waitcnt vmcnt(6)" ::: "memory");
    else if (t == NT - 2) asm volatile("s_waitcnt vmcnt(0)" ::: "memory");
    __builtin_amdgcn_s_barrier();
    __builtin_amdgcn_sched_barrier(0);
  }
#undef SG_A3
#undef SG_REST

  // epilogue: C = acc + resid (M_l divisible by 256 -> no guards)
  float* __restrict__ Cout = d.C[l];
  const float* __restrict__ Resid = d.R[l];
  const int rb = (lane >> 4) << 2;
  const int col0 = tN * 128 + wn + lr;
#pragma unroll
  for (int mi = 0; mi < 4; ++mi)
#pragma unroll
    for (int j = 0; j < 4; ++j) {
      const long row = (long)tM * 256 + wm + mi * 16 + rb + j;
      const long base = row * 256 + col0;
#pragma unroll
      for (int ni = 0; ni < 4; ++ni)
        Cout[base + ni * 16] = acc[mi][ni][j] + Resid[base + ni * 16];
    }
}

// ---------------- launch ---------------------------------------------------------
extern "C" void kernel_launch(void* const* d_in, const int* in_sizes, int n_in,
                              void* d_out, int out_size, void* d_ws, size_t ws_size,
                              hipStream_t stream) {
  const float* F1[4], * F2[4], * Uin[4], * Win[4];
  for (int l = 0; l < 4; ++l) {
    F1[l]  = (const float*)d_in[4 * l + 0];
    F2[l]  = (const float*)d_in[4 * l + 1];
    Uin[l] = (const float*)d_in[4 * l + 2];
    Win[l] = (const float*)d_in[4 * l + 3];
  }
  static const int  cin_[4]  = {1024, 2304, 2816, 2560};
  static const int  cum_[4]  = {0, 1024, 3328, 6144};
  static const long moff_[4] = {0, 524288, 2097152, 4718592};
  static const int  nBLK_[4] = {16, 48, 80, 112};   // (Ml/256)*2
  static const long asz_[4]  = {4194304L, 28311552L, 57671680L, 73400320L}; // bytes

  char* ws = (char*)d_ws;
  float*  cg   = (float*)ws;                        // 6664 B
  __bf16* Ubf  = (__bf16*)(ws + 8192);              // 4,456,448 B
  __bf16* Wtbf = (__bf16*)(ws + 8192 + 4456448);    // 524,288 B
  __bf16* UWt  = (__bf16*)(ws + 5242880);           // 4,456,448 B
  const long ABASE = 10485760;
  const bool big = ws_size >= (size_t)(ABASE + asz_[0] + asz_[1] + asz_[2] + asz_[3]);

  __bf16* Ab[4];
  if (big) {
    long off = ABASE;
    for (int l = 0; l < 4; ++l) { Ab[l] = (__bf16*)(ws + off); off += asz_[l]; }
  } else {
    for (int l = 0; l < 4; ++l) Ab[l] = (__bf16*)(ws + ABASE);
  }

  hipLaunchKernelGGL(prep, dim3(3207), dim3(256), 0, stream,
                     Uin[0], Uin[1], Uin[2], Uin[3],
                     Win[0], Win[1], Win[2], Win[3], Ubf, Wtbf, cg);

  GemmDesc gd;
  {
    int starts[4] = {0, 40, 84, 120};   // order l3,l2,l1,l0
    int lmap[4]   = {3, 2, 1, 0};
    for (int s = 0; s < 4; ++s) { gd.start[s] = starts[s]; gd.lmap[s] = lmap[s]; }
    for (int l = 0; l < 4; ++l) {
      gd.A[l] = Wtbf + (long)l * 65536;
      gd.B[l] = Ubf + (long)cum_[l] * 256;
      gd.C[l] = UWt + (long)cum_[l] * 256;
      gd.Kd[l] = 256;
      gd.Nc[l] = cin_[l];
    }
  }

  if (big) {
    // one launch: 136 UW-GEMM blocks + 1024 TP blocks (independent, overlap)
    hipLaunchKernelGGL((tp_uw<15>), dim3(1160), dim3(256), 0, stream,
                       F1[0], F1[1], F1[2], F1[3], F2[0], F2[1], F2[2], F2[3],
                       cg, Ab[0], Ab[1], Ab[2], Ab[3], gd, 136);
    MainDesc d;
    int starts[4] = {0, 80, 192, 240};   // l2(80,NT44) l3(112,NT40) l1(48,NT36) l0(16,NT16)
    int lmap[4]   = {2, 3, 1, 0};
    for (int s = 0; s < 4; ++s) { d.start[s] = starts[s]; d.lmap[s] = lmap[s]; }
    for (int l = 0; l < 4; ++l) {
      d.A[l] = Ab[l];
      d.B[l] = UWt + (long)cum_[l] * 256;
      d.C[l] = (float*)d_out + moff_[l];
      d.R[l] = F1[l];
      d.cin4[l] = cin_[l];
    }
    hipLaunchKernelGGL(gemm_main, dim3(256), dim3(512), 0, stream, d);
  } else {
    // fallback: UW first, then per-l TP + main GEMM reusing one A buffer
    hipLaunchKernelGGL((tp_uw<0>), dim3(136), dim3(256), 0, stream,
                       F1[0], F1[1], F1[2], F1[3], F2[0], F2[1], F2[2], F2[3],
                       cg, Ab[0], Ab[1], Ab[2], Ab[3], gd, 136);
    for (int l = 0; l < 4; ++l) {
      switch (l) {
        case 0: hipLaunchKernelGGL((tp_uw<1>), dim3(1024), dim3(256), 0, stream,
                  F1[0],F1[1],F1[2],F1[3], F2[0],F2[1],F2[2],F2[3], cg,
                  Ab[0],Ab[1],Ab[2],Ab[3], gd, 0); break;
        case 1: hipLaunchKernelGGL((tp_uw<2>), dim3(1024), dim3(256), 0, stream,
                  F1[0],F1[1],F1[2],F1[3], F2[0],F2[1],F2[2],F2[3], cg,
                  Ab[0],Ab[1],Ab[2],Ab[3], gd, 0); break;
        case 2: hipLaunchKernelGGL((tp_uw<4>), dim3(1024), dim3(256), 0, stream,
                  F1[0],F1[1],F1[2],F1[3], F2[0],F2[1],F2[2],F2[3], cg,
                  Ab[0],Ab[1],Ab[2],Ab[3], gd, 0); break;
        case 3: hipLaunchKernelGGL((tp_uw<8>), dim3(1024), dim3(256), 0, stream,
                  F1[0],F1[1],F1[2],F1[3], F2[0],F2[1],F2[2],F2[3], cg,
                  Ab[0],Ab[1],Ab[2],Ab[3], gd, 0); break;
      }
      MainDesc d;
      for (int s = 0; s < 4; ++s) {
        d.start[s] = (s == 0) ? 0 : 0x7fffffff;
        d.lmap[s] = l;
      }
      for (int ll = 0; ll < 4; ++ll) {
        d.A[ll] = Ab[l];
        d.B[ll] = UWt + (long)cum_[l] * 256;
        d.C[ll] = (float*)d_out + moff_[l];
        d.R[ll] = F1[l];
        d.cin4[ll] = cin_[l];
      }
      hipLaunchKernelGGL(gemm_main, dim3(nBLK_[l]), dim3(512), 0, stream, d);
    }
  }
  (void)in_sizes; (void)n_in; (void)out_size; (void)ws_size;
}